// Round 5
// baseline (326.078 us; speedup 1.0000x reference)
//
#include <hip/hip_runtime.h>

// Problem constants (fixed by reference)
#define H    256
#define HE   64
#define NPB  512         // nodes per batch
#define NA   512         // total anchors (8 batches * 64)
#define MU_STEP (20.0f / 63.0f)
#define INV_SIG 3.2f     // 1/0.3125
#define G_LD 384         // padded leading dim of fused G matrix (rows 0..319)

// ---------------------------------------------------------------------------
// Reductions
// ---------------------------------------------------------------------------
__device__ __forceinline__ float wave_sum(float v) {
#pragma unroll
    for (int o = 32; o; o >>= 1) v += __shfl_xor(v, o, 64);
    return v;
}
__device__ __forceinline__ float wave_max(float v) {
#pragma unroll
    for (int o = 32; o; o >>= 1) v = fmaxf(v, __shfl_xor(v, o, 64));
    return v;
}
__device__ __forceinline__ float block_sum(float v, float* red4, int t) {
    v = wave_sum(v);
    if ((t & 63) == 0) red4[t >> 6] = v;
    __syncthreads();
    v = red4[0] + red4[1] + red4[2] + red4[3];
    __syncthreads();
    return v;
}
__device__ __forceinline__ float block_max(float v, float* red4, int t) {
    v = wave_max(v);
    if ((t & 63) == 0) red4[t >> 6] = v;
    __syncthreads();
    v = fmaxf(fmaxf(red4[0], red4[1]), fmaxf(red4[2], red4[3]));
    __syncthreads();
    return v;
}

// ---------------------------------------------------------------------------
// K_W: weights prep (one dispatch, two roles by block id)
//  blocks 0..147 : transposes  W1T, W2T, W3T, KT (KT[c][r] = Wkv[256+r][c])
//  blocks 148..177: G = [Wq|bq]^T @ [Wkv | bkv_k]  (tiled 64x64, K=256)
//    G[j][n], j in [0,320) (row 256 = bq row -> g0; rows>256 zero),
//    n in [0,384) (cols 0..255 qW, 256..319 qe, 320 qbk; rest garbage-zero)
// ---------------------------------------------------------------------------
__global__ void __launch_bounds__(256) prep_weights(
    const float* __restrict__ Wq,  const float* __restrict__ bq,
    const float* __restrict__ Wkv, const float* __restrict__ bkv,
    const float* __restrict__ W1, const float* __restrict__ W2,
    const float* __restrict__ W3,
    float* __restrict__ G, float* __restrict__ KT,
    float* __restrict__ W1T, float* __restrict__ W2T, float* __restrict__ W3T)
{
    __shared__ float lds[8192];              // 32 KB (union of both roles)
    const int bid = blockIdx.x, t = threadIdx.x;

    if (bid < 148) {
        // ---------------- transpose role ----------------
        float (*tile)[65] = (float(*)[65])lds;   // 64x65 = 4160 floats
        const float* src; float* dst; int C, Rd, tr, tc;
        if (bid < 32)       { src = W1; dst = W1T; C = 256; Rd = 512; tr = bid >> 2; tc = bid & 3; }
        else if (bid < 96)  { int ti = bid - 32; src = W2; dst = W2T; C = 512; Rd = 512; tr = ti >> 3; tc = ti & 7; }
        else if (bid < 128) { int ti = bid - 96; src = W3; dst = W3T; C = 512; Rd = 256; tr = ti >> 3; tc = ti & 7; }
        else                { int ti = bid - 128; src = Wkv + 256 * 320; dst = KT; C = 320; Rd = 256; tr = ti / 5; tc = ti % 5; }
        const int lane = t & 63, rg = t >> 6;
#pragma unroll
        for (int i = 0; i < 16; ++i) {
            int r = rg * 16 + i;
            tile[r][lane] = src[(size_t)(tr * 64 + r) * C + tc * 64 + lane];
        }
        __syncthreads();
#pragma unroll
        for (int i = 0; i < 16; ++i) {
            int r = rg * 16 + i;
            dst[(size_t)(tc * 64 + r) * Rd + tr * 64 + lane] = tile[lane][r];
        }
    } else {
        // ---------------- G GEMM role ----------------
        float* Als = lds;                    // [64c][64j]
        float* Bls = lds + 4096;             // [64c][64n]
        const int gb = bid - 148;            // 0..29
        const int mt = gb / 6, nt = gb - mt * 6;
        const int m0 = mt * 64, n0 = nt * 64;
        const int nq = t & 15, mq = t >> 4;

        float acc[4][4];
#pragma unroll
        for (int i = 0; i < 4; ++i)
#pragma unroll
            for (int k = 0; k < 4; ++k) acc[i][k] = 0.f;

        for (int c0 = 0; c0 < 256; c0 += 64) {
            for (int idx = t; idx < 4096; idx += 256) {
                int cl = idx >> 6, el = idx & 63;
                int c = c0 + cl;
                int j = m0 + el;
                Als[idx] = (j < 256) ? Wq[(size_t)c * 256 + j]
                                     : (j == 256 ? bq[c] : 0.f);
                int n = n0 + el;
                Bls[idx] = (n < 320) ? Wkv[(size_t)c * 320 + n]
                                     : (n == 320 ? bkv[c] : 0.f);
            }
            __syncthreads();
#pragma unroll 4
            for (int cl = 0; cl < 64; ++cl) {
                const float* ar = Als + cl * 64 + mq * 4;
                const float* br = Bls + cl * 64 + nq * 4;
#pragma unroll
                for (int i = 0; i < 4; ++i)
#pragma unroll
                    for (int k = 0; k < 4; ++k)
                        acc[i][k] = fmaf(ar[i], br[k], acc[i][k]);
            }
            __syncthreads();
        }
#pragma unroll
        for (int i = 0; i < 4; ++i) {
            int j = m0 + mq * 4 + i;
            float* gr = G + (size_t)j * G_LD + n0 + nq * 4;
            gr[0] = acc[i][0]; gr[1] = acc[i][1];
            gr[2] = acc[i][2]; gr[3] = acc[i][3];
        }
    }
}

// ---------------------------------------------------------------------------
// K_A: per-anchor [qW|qe|qbk] = af @ G + g0 (g0 = G row 256). 512 blocks.
// All G reads lane-coalesced; af via LDS broadcast. No serial q->qW chain.
// ---------------------------------------------------------------------------
__global__ void __launch_bounds__(256) anchor_kernel(
    const float* __restrict__ anchor_f, const float* __restrict__ G,
    float* __restrict__ qWT, float* __restrict__ qe_ws, float* __restrict__ qbk_ws)
{
    const int a = blockIdx.x, b = a >> 6, la = a & 63, t = threadIdx.x;
    __shared__ float af_s[H];
    af_s[t] = anchor_f[(size_t)a * H + t];
    __syncthreads();

    const bool hasB = (t <= 64);
    const int  nB   = 256 + t;
    float acc_a = G[(size_t)256 * G_LD + t];
    float acc_b = hasB ? G[(size_t)256 * G_LD + nB] : 0.f;
#pragma unroll 8
    for (int j = 0; j < H; ++j) {
        float av = af_s[j];
        acc_a = fmaf(av, G[(size_t)j * G_LD + t], acc_a);
        if (hasB) acc_b = fmaf(av, G[(size_t)j * G_LD + nB], acc_b);
    }
    qWT[((size_t)b * H + t) * 64 + la] = acc_a;          // [b][k][la]
    if (t < 64)       qe_ws[(size_t)a * 64 + t] = acc_b; // [a][j]
    else if (t == 64) qbk_ws[a] = acc_b;
}

// ---------------------------------------------------------------------------
// K_L: logits. grid 512 = (batch, 8-node chunk); 256 thr = 64 anchors x 4 grps.
// node_f staged once in LDS; qWT loads coalesced; lgT layout [b][n][la].
// ---------------------------------------------------------------------------
__global__ void __launch_bounds__(256) logits_kernel(
    const float* __restrict__ anchor_x, const float* __restrict__ node_x,
    const float* __restrict__ node_f,   const float* __restrict__ node_mask,
    const float* __restrict__ qWT, const float* __restrict__ qe_ws,
    const float* __restrict__ qbk_ws, float* __restrict__ lgT)
{
    const int bid = blockIdx.x, b = bid >> 6, chunk = bid & 63, n0 = chunk * 8;
    const int t = threadIdx.x, la = t & 63, ng = t >> 6;

    __shared__ float nf_s[8 * H];
    __shared__ float qe_s[64 * 65];      // [j][la], padded
    __shared__ float nx_s[8][4];
    __shared__ float mf_s[8];

    {
        const float4* src = (const float4*)(node_f + ((size_t)b * NPB + n0) * H);
        float4* dst = (float4*)nf_s;
        dst[t] = src[t];
        dst[t + 256] = src[t + 256];
    }
#pragma unroll
    for (int i = 0; i < 16; ++i) {
        int e = t + i * 256;                       // e = la_src*64 + j
        qe_s[(e & 63) * 65 + (e >> 6)] = qe_ws[(size_t)b * 4096 + e];
    }
    if (t < 8) {
        mf_s[t] = (node_mask[b * NPB + n0 + t] - 1.0f) * 1000000.0f;
        nx_s[t][0] = node_x[3 * (b * NPB + n0 + t) + 0];
        nx_s[t][1] = node_x[3 * (b * NPB + n0 + t) + 1];
        nx_s[t][2] = node_x[3 * (b * NPB + n0 + t) + 2];
    }
    __syncthreads();

    const float ax0 = anchor_x[3 * (b * 64 + la) + 0];
    const float ax1 = anchor_x[3 * (b * 64 + la) + 1];
    const float ax2 = anchor_x[3 * (b * 64 + la) + 2];
    const float qbk = qbk_ws[b * 64 + la];

    float acc0 = 0.f, acc1 = 0.f;
    {
        const float* qwcol = qWT + (size_t)b * H * 64 + la;
        const float* r0 = nf_s + ng * H;
        const float* r1 = nf_s + (ng + 4) * H;
#pragma unroll 8
        for (int k = 0; k < H; ++k) {
            float w = qwcol[(size_t)k * 64];
            acc0 = fmaf(w, r0[k], acc0);
            acc1 = fmaf(w, r1[k], acc1);
        }
    }
#pragma unroll
    for (int nn = 0; nn < 2; ++nn) {
        int nl = ng + nn * 4;
        float dx = ax0 - nx_s[nl][0] + 1e-8f;
        float dy = ax1 - nx_s[nl][1] + 1e-8f;
        float dz = ax2 - nx_s[nl][2] + 1e-8f;
        float d10 = sqrtf(dx * dx + dy * dy + dz * dz) * 0.1f;
        float le = 0.f;
#pragma unroll 8
        for (int j = 0; j < HE; ++j) {
            float u = (d10 - j * MU_STEP) * INV_SIG;
            le += qe_s[j * 65 + la] * __expf(-u * u);
        }
        float lg = ((nn ? acc1 : acc0) + le + qbk) * mf_s[nl];
        lgT[((size_t)b * NPB + n0 + nl) * 64 + la] = lg;
    }
}

// ---------------------------------------------------------------------------
// K_R: per-anchor softmax + winner compaction + upd (coalesced KT) + LN1.
// ---------------------------------------------------------------------------
__global__ void __launch_bounds__(256) reduce_kernel(
    const float* __restrict__ anchor_x, const float* __restrict__ node_x,
    const float* __restrict__ anchor_f, const float* __restrict__ node_f,
    const float* __restrict__ lgT, const float* __restrict__ KT,
    const float* __restrict__ bkv,
    const float* __restrict__ ln1_g, const float* __restrict__ ln1_b,
    float* __restrict__ af1_out)
{
    const int a = blockIdx.x, b = a >> 6, la = a & 63, t = threadIdx.x;
    __shared__ float w_s[NPB], snf_s[H], rj_s[HE], red[256], red4[4];
    __shared__ int idx_s[NPB];
    __shared__ int cnt_s;
    if (t == 0) cnt_s = 0;

    float lg0 = lgT[((size_t)b * NPB + t) * 64 + la];
    float lg1 = lgT[((size_t)b * NPB + t + 256) * 64 + la];

    float gm = block_max(fmaxf(lg0, lg1), red4, t);   // also publishes cnt_s=0
    float e0 = __expf(lg0 - gm);
    float e1 = __expf(lg1 - gm);
    w_s[t] = e0; w_s[t + 256] = e1;
    float inv = 1.0f / block_sum(e0 + e1, red4, t);   // syncs publish w_s

    if (e0 > 0.f) { int p = atomicAdd(&cnt_s, 1); idx_s[p] = t; }
    if (e1 > 0.f) { int p = atomicAdd(&cnt_s, 1); idx_s[p] = t + 256; }
    __syncthreads();
    const int cnt = cnt_s;

    // snf[t] = sum_winners w_n * node_f[n, t]
    {
        float s = 0.f;
        const float* base = node_f + (size_t)(b * NPB) * H + t;
        for (int i = 0; i < cnt; ++i) {
            int n = idx_s[i];
            s += w_s[n] * base[(size_t)n * H];
        }
        snf_s[t] = s;
    }
    // rj[j] = sum_winners w_n * rbf[n, j]  (d10 recomputed, same fp order as K_L)
    {
        const float ax0 = anchor_x[3 * a + 0];
        const float ax1 = anchor_x[3 * a + 1];
        const float ax2 = anchor_x[3 * a + 2];
        int j = t & 63, g = t >> 6;
        float mu = j * MU_STEP;
        float r = 0.f;
        for (int i = g; i < cnt; i += 4) {
            int n = idx_s[i];
            int ngi = b * NPB + n;
            float dx = ax0 - node_x[3 * ngi + 0] + 1e-8f;
            float dy = ax1 - node_x[3 * ngi + 1] + 1e-8f;
            float dz = ax2 - node_x[3 * ngi + 2] + 1e-8f;
            float d10 = sqrtf(dx * dx + dy * dy + dz * dz) * 0.1f;
            float u = (d10 - mu) * INV_SIG;
            r += w_s[n] * __expf(-u * u);
        }
        red[t] = r;
        __syncthreads();
        if (t < 64) rj_s[t] = red[t] + red[t + 64] + red[t + 128] + red[t + 192];
        __syncthreads();
    }

    // upd[t] = (sum_c KT[c][t]*snf[c] + sum_j KT[256+j][t]*rj[j]) * inv + bkv_v[t]
    float upd;
    {
        float u = 0.f;
#pragma unroll 8
        for (int c = 0; c < H; ++c)
            u = fmaf(KT[(size_t)c * H + t], snf_s[c], u);
        float e = 0.f;
#pragma unroll 8
        for (int j = 0; j < HE; ++j)
            e = fmaf(KT[(size_t)(H + j) * H + t], rj_s[j], e);
        upd = (u + e) * inv + bkv[H + t];
    }

    // residual + LN1
    float x    = anchor_f[(size_t)a * H + t] + upd;
    float mean = block_sum(x, red4, t) * (1.0f / 256.0f);
    float xc   = x - mean;
    float var  = block_sum(xc * xc, red4, t) * (1.0f / 256.0f);
    af1_out[(size_t)a * H + t] = xc * rsqrtf(var + 1e-5f) * ln1_g[t] + ln1_b[t];
}

// ---------------------------------------------------------------------------
// MLP GEMM (W transposed): out[a][n] = act(sum_k A[a][k]*WT[k][n] + b[n])
// Block: 16 anchors x 64 cols, 512 threads, 2 outputs/thread.
// ---------------------------------------------------------------------------
template<bool RELU>
__global__ void __launch_bounds__(512) mlp_gemm(
    const float* __restrict__ A, const float* __restrict__ WT,
    const float* __restrict__ bias, float* __restrict__ out,
    int K, int N)
{
    extern __shared__ float As[];                    // [16][K]
    const int t  = threadIdx.x;
    const int tn = t & 63, tg = t >> 6;
    const int a0 = blockIdx.x * 16;
    const int n  = blockIdx.y * 64 + tn;

    {
        const float4* src = (const float4*)(A + (size_t)a0 * K);
        float4* dst = (float4*)As;
        for (int p = t; p < 4 * K; p += 512) dst[p] = src[p];
    }
    __syncthreads();

    float acc0 = bias[n], acc1 = acc0;
    const float* w = WT + n;
    const float* r0 = As + (size_t)tg * K;
    const float* r1 = As + (size_t)(tg + 8) * K;
#pragma unroll 8
    for (int k = 0; k < K; ++k) {
        float wv = w[(size_t)k * N];
        acc0 = fmaf(r0[k], wv, acc0);
        acc1 = fmaf(r1[k], wv, acc1);
    }
    if (RELU) { acc0 = fmaxf(acc0, 0.f); acc1 = fmaxf(acc1, 0.f); }
    out[(size_t)(a0 + tg) * N + n]     = acc0;
    out[(size_t)(a0 + tg + 8) * N + n] = acc1;
}

// ---------------------------------------------------------------------------
// K_M3: y = m2 @ W3T + b3, then residual(af1) + LN2 -> out.
// grid 32 x 512 thr; block = 16 anchors x all 256 cols; LN via wave shuffle.
// Thread: anchors {a0+w, a0+w+8} (w = wave id), cols {la, la+64, la+128, la+192}.
// ---------------------------------------------------------------------------
__global__ void __launch_bounds__(512) mlp3_ln2(
    const float* __restrict__ A, const float* __restrict__ W3T,
    const float* __restrict__ b3, const float* __restrict__ af1,
    const float* __restrict__ g2, const float* __restrict__ bb2,
    float* __restrict__ out)
{
    __shared__ float As[16 * 512];                   // 32 KB
    const int t = threadIdx.x, w = t >> 6, la = t & 63;
    const int a0 = blockIdx.x * 16;

    {
        const float4* src = (const float4*)(A + (size_t)a0 * 512);
        float4* dst = (float4*)As;
        for (int p = t; p < 2048; p += 512) dst[p] = src[p];
    }
    __syncthreads();

    float acc0[4], acc1[4];
#pragma unroll
    for (int i = 0; i < 4; ++i) { acc0[i] = b3[la + 64 * i]; acc1[i] = acc0[i]; }

    const float* r0 = As + (size_t)w * 512;
    const float* r1 = As + (size_t)(w + 8) * 512;
#pragma unroll 4
    for (int k = 0; k < 512; ++k) {
        float a0v = r0[k], a1v = r1[k];
        const float* wr = W3T + (size_t)k * 256 + la;
#pragma unroll
        for (int i = 0; i < 4; ++i) {
            float wv = wr[64 * i];
            acc0[i] = fmaf(a0v, wv, acc0[i]);
            acc1[i] = fmaf(a1v, wv, acc1[i]);
        }
    }

    float gv[4], bv[4];
#pragma unroll
    for (int i = 0; i < 4; ++i) { gv[i] = g2[la + 64 * i]; bv[i] = bb2[la + 64 * i]; }

#pragma unroll
    for (int aa = 0; aa < 2; ++aa) {
        int ar = a0 + w + aa * 8;
        float* acc = aa ? acc1 : acc0;
        float y[4], s = 0.f;
#pragma unroll
        for (int i = 0; i < 4; ++i) {
            y[i] = acc[i] + af1[(size_t)ar * 256 + la + 64 * i];
            s += y[i];
        }
        float mean = wave_sum(s) * (1.0f / 256.0f);
        float v = 0.f;
#pragma unroll
        for (int i = 0; i < 4; ++i) { y[i] -= mean; v += y[i] * y[i]; }
        float rs = rsqrtf(wave_sum(v) * (1.0f / 256.0f) + 1e-5f);
#pragma unroll
        for (int i = 0; i < 4; ++i)
            out[(size_t)ar * 256 + la + 64 * i] = y[i] * rs * gv[i] + bv[i];
    }
}

// ---------------------------------------------------------------------------
extern "C" void kernel_launch(void* const* d_in, const int* in_sizes, int n_in,
                              void* d_out, int out_size, void* d_ws, size_t ws_size,
                              hipStream_t stream)
{
    const float* anchor_x  = (const float*)d_in[0];
    const float* node_x    = (const float*)d_in[1];
    const float* anchor_f  = (const float*)d_in[2];
    const float* node_f    = (const float*)d_in[3];
    const float* node_mask = (const float*)d_in[6];
    const float* Wq        = (const float*)d_in[7];
    const float* bq        = (const float*)d_in[8];
    const float* Wkv       = (const float*)d_in[9];
    const float* bkv       = (const float*)d_in[10];
    const float* ln1_g     = (const float*)d_in[11];
    const float* ln1_b     = (const float*)d_in[12];
    const float* W1        = (const float*)d_in[13];
    const float* b1        = (const float*)d_in[14];
    const float* W2        = (const float*)d_in[15];
    const float* b2        = (const float*)d_in[16];
    const float* W3        = (const float*)d_in[17];
    const float* b3        = (const float*)d_in[18];
    const float* ln2_g     = (const float*)d_in[19];
    const float* ln2_b     = (const float*)d_in[20];

    float* ws     = (float*)d_ws;
    float* G      = ws;                 // 320*384  = 122880
    float* qWT    = G      + 122880;    // 8*256*64 = 131072
    float* qe_ws  = qWT    + 131072;    // 512*64   = 32768
    float* qbk_ws = qe_ws  + 32768;     // 512 (pad 1024)
    float* lgT    = qbk_ws + 1024;      // 8*512*64 = 262144
    float* af1    = lgT    + 262144;    // 512*256  = 131072
    float* m1     = af1    + 131072;    // 512*512  = 262144
    float* m2     = m1     + 262144;    // 512*512  = 262144
    float* KT     = m2     + 262144;    // 320*256  = 81920
    float* W1T    = KT     + 81920;     // 256*512  = 131072
    float* W2T    = W1T    + 131072;    // 512*512  = 262144
    float* W3T    = W2T    + 262144;    // 512*256  = 131072
    // total ~7.3 MB

    prep_weights<<<178, 256, 0, stream>>>(Wq, bq, Wkv, bkv, W1, W2, W3,
                                          G, KT, W1T, W2T, W3T);

    anchor_kernel<<<NA, 256, 0, stream>>>(anchor_f, G, qWT, qe_ws, qbk_ws);

    logits_kernel<<<512, 256, 0, stream>>>(anchor_x, node_x, node_f, node_mask,
                                           qWT, qe_ws, qbk_ws, lgT);

    reduce_kernel<<<NA, 256, 0, stream>>>(anchor_x, node_x, anchor_f, node_f,
                                          lgT, KT, bkv, ln1_g, ln1_b, af1);

    mlp_gemm<true><<<dim3(32, 8), 512, 16 * 256 * 4, stream>>>(af1, W1T, b1, m1, 256, 512);
    mlp_gemm<true><<<dim3(32, 8), 512, 16 * 512 * 4, stream>>>(m1,  W2T, b2, m2, 512, 512);

    mlp3_ln2<<<32, 512, 0, stream>>>(m2, W3T, b3, af1, ln2_g, ln2_b, (float*)d_out);
}